// Round 7
// baseline (147.028 us; speedup 1.0000x reference)
//
#include <hip/hip_runtime.h>
#include <hip/hip_bf16.h>

#define H_ 4
#define B_ 16
#define T_ 4000
#define E_ 512
#define D_ 512
#define A_ 128
#define C_ 10
#define K_ 101
#define O_ 512
#define TC_ 50
#define CH_ (T_ / TC_)   // 80

typedef __attribute__((ext_vector_type(16))) float f32x16;
typedef __attribute__((ext_vector_type(8)))  short short8;

#define MFMA32(a, b, c) __builtin_amdgcn_mfma_f32_32x32x16_bf16(a, b, c, 0, 0, 0)

#define GLL16(gp, lp) __builtin_amdgcn_global_load_lds( \
    (const __attribute__((address_space(1))) unsigned int*)(gp), \
    (__attribute__((address_space(3))) unsigned int*)(lp), 16, 0, 0)

static __device__ __forceinline__ unsigned short f2bf(float x) {
  unsigned u = __float_as_uint(x);
  unsigned r = (u + 0x7FFFu + ((u >> 16) & 1u)) >> 16;
  return (unsigned short)r;
}
static __device__ __forceinline__ unsigned pk2(float a, float b) {
  return (unsigned)f2bf(a) | ((unsigned)f2bf(b) << 16);
}
// single-instruction packed f32x2 -> bf16x2 (RNE)
static __device__ __forceinline__ unsigned cvtpk(float lo, float hi) {
  unsigned r;
  asm("v_cvt_pk_bf16_f32 %0, %1, %2" : "=v"(r) : "v"(lo), "v"(hi));
  return r;
}
static __device__ __forceinline__ uint4 packbf8(float4 f0, float4 f1) {
  uint4 u;
  u.x = cvtpk(f0.x, f0.y); u.y = cvtpk(f0.z, f0.w);
  u.z = cvtpk(f1.x, f1.y); u.w = cvtpk(f1.z, f1.w);
  return u;
}
static __device__ __forceinline__ f32x16 zero16() {
  f32x16 z;
#pragma unroll
  for (int i = 0; i < 16; ++i) z[i] = 0.f;
  return z;
}
static __device__ __forceinline__ float tanh_fast(float x) {
  return 1.0f - 2.0f / (__expf(2.0f * x) + 1.0f);
}
// swizzled byte offset for 32-k-wide bf16 tiles packed as 2 rows per 128B line
static __device__ __forceinline__ int swz32(int r, int ksg) {
  return (r >> 1) * 128 + (((((r & 1) << 2) | ksg) ^ ((r >> 1) & 7)) << 4);
}
// swizzled byte offset for 64-elem-wide bf16 rows (128B per row)
static __device__ __forceinline__ int swzC(int r, int sl) {
  return r * 128 + ((sl ^ (r & 7)) << 4);
}

// ---------------------------------------------------------------------------
// k_prep: (a) wbs = pre-swizzled bf16 Wenc [16 kt][512 n][32 k]; each 256-col
// half of a kt-slab is a contiguous 16KB block (used by the N-split blocks).
// (b) wattb = pre-swizzled bf16 padded Watt. (c) addv4 = 4-way split-K
// partials of benc + dec_z@Wdec, layout [p][b][h][a].
__global__ __launch_bounds__(256) void k_prep(const float* __restrict__ Wenc,
                                              const float* __restrict__ Watt,
                                              const float* __restrict__ dec_z,
                                              const float* __restrict__ Wdec,
                                              const float* __restrict__ benc,
                                              char* __restrict__ wbs,
                                              char* __restrict__ wattb,
                                              float* __restrict__ addv4) {
  const int bid = blockIdx.x;
  const int tid = threadIdx.x;
  if (bid < 128) {
    const int c = bid * 256 + tid;          // 16B chunk index into wbs
    const int cc = c & 2047;
    const int kt = c >> 11;
    const int line = cc >> 3, sp = cc & 7;
    const int sraw = sp ^ (line & 7);
    const int n = line * 2 + (sraw >> 2);
    const int ksg = sraw & 3;
    const int h = n >> 7, a = n & 127;
    const int kb = kt * 32 + ksg * 8;
    uint4 u;
    u.x = pk2(Wenc[((size_t)h * E_ + kb + 0) * A_ + a], Wenc[((size_t)h * E_ + kb + 1) * A_ + a]);
    u.y = pk2(Wenc[((size_t)h * E_ + kb + 2) * A_ + a], Wenc[((size_t)h * E_ + kb + 3) * A_ + a]);
    u.z = pk2(Wenc[((size_t)h * E_ + kb + 4) * A_ + a], Wenc[((size_t)h * E_ + kb + 5) * A_ + a]);
    u.w = pk2(Wenc[((size_t)h * E_ + kb + 6) * A_ + a], Wenc[((size_t)h * E_ + kb + 7) * A_ + a]);
    ((uint4*)wbs)[c] = u;
  } else if (bid == 128) {
#pragma unroll
    for (int q = 0; q < 4; ++q) {
      const int cw = q * 256 + tid;
      const int h = cw >> 8, cc = cw & 255;
      const int line = cc >> 3, sp = cc & 7;
      const int sraw = sp ^ (line & 7);
      const int a = line * 4 + (sraw >> 1);
      const int s = sraw & 1;
      unsigned short v[8];
#pragma unroll
      for (int j = 0; j < 8; ++j) {
        const int k = s * 8 + j;
        v[j] = (k < C_) ? f2bf(Watt[((size_t)h * C_ + k) * A_ + a]) : (unsigned short)0;
      }
      uint4 u;
      u.x = (unsigned)v[0] | ((unsigned)v[1] << 16);
      u.y = (unsigned)v[2] | ((unsigned)v[3] << 16);
      u.z = (unsigned)v[4] | ((unsigned)v[5] << 16);
      u.w = (unsigned)v[6] | ((unsigned)v[7] << 16);
      ((uint4*)wattb)[cw] = u;
    }
  } else {
    const int idx = bid - 129;
    const int b = idx >> 3, h = (idx >> 1) & 3, ks = idx & 1;
    const int a = tid & 127, kh = tid >> 7;
    const int p = ks * 2 + kh;
    const int d0 = p * 128;
    const float* z = dec_z + (size_t)b * D_ + d0;
    const float* w = Wdec + ((size_t)h * D_ + d0) * A_ + a;
    float s = (p == 0) ? benc[h * A_ + a] : 0.f;
#pragma unroll 8
    for (int d = 0; d < 128; ++d) s += z[d] * w[(size_t)d * A_];
    addv4[(((size_t)p * B_ + b) * H_ + h) * A_ + a] = s;
  }
}

// ---------------------------------------------------------------------------
__global__ __launch_bounds__(256) void k_conv(const float* __restrict__ att_prev,
                                              const float* __restrict__ conv_w,
                                              char* __restrict__ convpad) {
  const int bh = blockIdx.x;
  const int b = bh / H_, h = bh % H_;
  const int t0 = blockIdx.y * 256;
  __shared__ float ap[256 + K_ - 1 + 3];
  __shared__ float cw[C_ * K_];
  const float* src = att_prev + ((size_t)h * B_ + b) * T_;
  for (int i = threadIdx.x; i < 256 + K_ - 1; i += 256) {
    int tt = t0 - (K_ / 2) + i;
    ap[i] = (tt >= 0 && tt < T_) ? src[tt] : 0.f;
  }
  for (int i = threadIdx.x; i < C_ * K_; i += 256) cw[i] = conv_w[(size_t)h * C_ * K_ + i];
  __syncthreads();
  const int t = t0 + threadIdx.x;
  if (t < T_) {
    float s[C_];
#pragma unroll
    for (int c = 0; c < C_; ++c) s[c] = 0.f;
    for (int k = 0; k < K_; ++k) {
      float apv = ap[threadIdx.x + k];
#pragma unroll
      for (int c = 0; c < C_; ++c) s[c] += cw[c * K_ + k] * apv;
    }
    uint4 u0, u1;
    u0.x = pk2(s[0], s[1]); u0.y = pk2(s[2], s[3]);
    u0.z = pk2(s[4], s[5]); u0.w = pk2(s[6], s[7]);
    u1.x = pk2(s[8], s[9]); u1.y = 0u; u1.z = 0u; u1.w = 0u;
    char* dst = convpad + (size_t)(b * T_ + t) * 128 + h * 32;
    *(uint4*)dst = u0;
    *(uint4*)(dst + 16) = u1;
  }
}

// ---------------------------------------------------------------------------
// Fused MFMA, N-SPLIT: block = 128 rows x 256 cols (heads {2nh, 2nh+1}).
// 8 waves: wm(2 M-halves) x wn(4 N-quarters of 64 cols); per-wave 64x64 ->
// acc[2][2] = 64 AGPRs. __launch_bounds__(512,4): cap 128 regs/wave -> 2
// blocks/CU co-resident (the round-2..6 acc[2][4]=128-AGPR version was pinned
// at 2 waves/SIMD, 1 block/CU, 20% occupancy = no barrier overlap, 87us flat).
// LDS 48KB: A0=0(8K) A1=8192 B0=16384(16K) B1=32768(16K).
__global__ __launch_bounds__(512, 4) void k_fused_e_mfma(
    const float* __restrict__ enc,
    const char*  __restrict__ wbs,
    const char*  __restrict__ convpad,
    const char*  __restrict__ wattb,
    const float* __restrict__ addv4,
    const float* __restrict__ gv,
    float* __restrict__ e_out) {
  __shared__ char smem[49152];
  const int tid = threadIdx.x;
  const int wv = tid >> 6;
  const int wm = wv >> 2;       // M-half (rows wm*64..+63)
  const int wn = wv & 3;        // N-quarter (cols wn*64..+63 of 256)
  const int lane = tid & 63;
  const int ln31 = lane & 31;
  const int hi = lane >> 5;
  const int m0 = blockIdx.x * 128;
  const int nh = blockIdx.y;    // heads 2nh, 2nh+1
  const unsigned b0 = (unsigned)m0 / 4000u;
  const unsigned b1 = (unsigned)(m0 + 127) / 4000u;

  f32x16 acc[2][2];
#pragma unroll
  for (int i = 0; i < 2; ++i)
#pragma unroll
    for (int j = 0; j < 2; ++j) acc[i][j] = zero16();

  // invariant addresses
  const int srow = tid >> 2, sksg = tid & 3;      // A-stage: 4 thr/row, 32B
  char* wrA = smem + swz32(srow, sksg);           // +8192 for A1
  const float* encP = enc + (size_t)(m0 + srow) * E_ + sksg * 8;
  const char* wp = wbs + nh * 16384 + wv * 2048 + lane * 16;  // += 32768/kt
  char* gllB0 = smem + 16384 + wv * 2048;
  char* gllB1 = smem + 32768 + wv * 2048;
  const int aoff = swz32(wm * 64 + ln31, hi);
  const int boff = swz32(wn * 64 + ln31, hi);
  const char* pA  = smem + aoff;
  const char* pAx = smem + (aoff ^ 32);
  const char* pB  = smem + 16384 + boff;
  const char* pBx = smem + 16384 + (boff ^ 32);

#define MSTEP(AOFF, BOFF) do {                                                   \
    { short8 a0_ = *(const short8*)(pA  + (AOFF));                               \
      short8 a1_ = *(const short8*)(pA  + (AOFF) + 2048);                        \
      short8 b0_ = *(const short8*)(pB  + (BOFF));                               \
      short8 b1_ = *(const short8*)(pB  + (BOFF) + 2048);                        \
      acc[0][0] = MFMA32(a0_, b0_, acc[0][0]);                                   \
      acc[1][0] = MFMA32(a1_, b0_, acc[1][0]);                                   \
      acc[0][1] = MFMA32(a0_, b1_, acc[0][1]);                                   \
      acc[1][1] = MFMA32(a1_, b1_, acc[1][1]); }                                 \
    { short8 a0_ = *(const short8*)(pAx + (AOFF));                               \
      short8 a1_ = *(const short8*)(pAx + (AOFF) + 2048);                        \
      short8 b0_ = *(const short8*)(pBx + (BOFF));                               \
      short8 b1_ = *(const short8*)(pBx + (BOFF) + 2048);                        \
      acc[0][0] = MFMA32(a0_, b0_, acc[0][0]);                                   \
      acc[1][0] = MFMA32(a1_, b0_, acc[1][0]);                                   \
      acc[0][1] = MFMA32(a0_, b1_, acc[0][1]);                                   \
      acc[1][1] = MFMA32(a1_, b1_, acc[1][1]); }                                 \
  } while (0)

#define CBAR(N) do {                                                            \
    asm volatile("s_waitcnt vmcnt(" #N ") lgkmcnt(0)" ::: "memory");            \
    __builtin_amdgcn_sched_barrier(0);                                          \
    __builtin_amdgcn_s_barrier();                                               \
  } while (0)

  float4 rA0, rA1, rB0, rB1;

  // ---- prologue: GLL B0 (oldest), load kt0+kt1 raw, pack kt0 -> A0
  GLL16(wp, gllB0);
  GLL16(wp + 1024, gllB0 + 1024);
  __builtin_amdgcn_sched_barrier(0);
  {
    float4 t0 = ((const float4*)encP)[0];
    float4 t1 = ((const float4*)encP)[1];
    rA0 = ((const float4*)(encP + 32))[0];
    rA1 = ((const float4*)(encP + 32))[1];
    *(uint4*)wrA = packbf8(t0, t1);
  }
  encP += 64;       // -> kt2
  wp += 32768;      // -> B(kt1) source
  CBAR(2);

#pragma unroll 1
  for (int ktp = 0; ktp < 7; ++ktp) {
    // even kt: MFMA buf0; GLL B(kt+1)->B1; load rB=enc[kt+2]; pack rA->A1
    GLL16(wp, gllB1);
    GLL16(wp + 1024, gllB1 + 1024);
    __builtin_amdgcn_sched_barrier(0);
    rB0 = ((const float4*)encP)[0];
    rB1 = ((const float4*)encP)[1];
    __builtin_amdgcn_sched_barrier(0);
    MSTEP(0, 0);
    *(uint4*)(wrA + 8192) = packbf8(rA0, rA1);
    encP += 32; wp += 32768;
    CBAR(2);
    // odd kt: MFMA buf1; GLL->B0; load rA=enc[kt+2]; pack rB->A0
    GLL16(wp, gllB0);
    GLL16(wp + 1024, gllB0 + 1024);
    __builtin_amdgcn_sched_barrier(0);
    rA0 = ((const float4*)encP)[0];
    rA1 = ((const float4*)encP)[1];
    __builtin_amdgcn_sched_barrier(0);
    MSTEP(8192, 16384);
    *(uint4*)wrA = packbf8(rB0, rB1);
    encP += 32; wp += 32768;
    CBAR(2);
  }

  // kt=14: MFMA buf0; GLL B15->B1; pack rA(enc kt15)->A1; drain
  GLL16(wp, gllB1);
  GLL16(wp + 1024, gllB1 + 1024);
  __builtin_amdgcn_sched_barrier(0);
  MSTEP(0, 0);
  *(uint4*)(wrA + 8192) = packbf8(rA0, rA1);
  CBAR(0);

  // kt=15: MFMA buf1; GLL Watt(2 heads, 8KB)->A0; stage conv rows->B0; drain
  {
    GLL16(wattb + nh * 8192 + wv * 1024 + lane * 16, smem + wv * 1024);
    __builtin_amdgcn_sched_barrier(0);
    uint4 rc0 = *(const uint4*)(convpad + (size_t)(m0 + (tid >> 3)) * 128 + (tid & 7) * 16);
    uint4 rc1 = *(const uint4*)(convpad + (size_t)(m0 + ((tid + 512) >> 3)) * 128 + (tid & 7) * 16);
    __builtin_amdgcn_sched_barrier(0);
    MSTEP(8192, 16384);
    *(uint4*)(smem + 16384 + swzC(tid >> 3, tid & 7)) = rc0;
    *(uint4*)(smem + 16384 + swzC((tid + 512) >> 3, tid & 7)) = rc1;
    CBAR(0);
  }

  const int head_l = wn >> 1;             // local head 0/1
  const int h_glob = nh * 2 + head_l;

  // conv MFMA step (K=16): A = conv features (B0), B = Watt (A0)
  {
    const char* AconvL = smem + 16384;
    const char* WattL  = smem + head_l * 4096;
    const int sl = h_glob * 2 + hi;
    short8 ac0 = *(const short8*)(AconvL + swzC(wm * 64 + ln31, sl));
    short8 ac1 = *(const short8*)(AconvL + swzC(wm * 64 + 32 + ln31, sl));
#pragma unroll
    for (int bi = 0; bi < 2; ++bi) {
      const int ar = (wn & 1) * 64 + bi * 32 + ln31;
      short8 wf = *(const short8*)(WattL + (ar >> 2) * 128 +
                                   (((((ar & 3) << 1) | hi) ^ ((ar >> 2) & 7)) << 4));
      acc[0][bi] = MFMA32(ac0, wf, acc[0][bi]);
      acc[1][bi] = MFMA32(ac1, wf, acc[1][bi]);
    }
  }

  // epilogue: + addv, tanh, dot gv, 32-lane reduce -> per-wave 64-col partials
  {
    float av0v[2], av1v[2], gvr[2];
#pragma unroll
    for (int bi = 0; bi < 2; ++bi) {
      const int col = (wn & 1) * 64 + bi * 32 + ln31;  // col within head
      const int i0 = (b0 * H_ + h_glob) * A_ + col;
      const int i1 = (b1 * H_ + h_glob) * A_ + col;
      av0v[bi] = addv4[i0] + addv4[8192 + i0] + addv4[16384 + i0] + addv4[24576 + i0];
      av1v[bi] = addv4[i1] + addv4[8192 + i1] + addv4[16384 + i1] + addv4[24576 + i1];
      gvr[bi] = gv[h_glob * A_ + col];
    }
    float* P = (float*)(smem + 8192);     // 8 waves x 64 rows
#pragma unroll
    for (int mi = 0; mi < 2; ++mi) {
#pragma unroll
      for (int reg = 0; reg < 16; ++reg) {
        const int rl = wm * 64 + mi * 32 + (reg & 3) + ((reg >> 2) << 3) + (hi << 2);
        const unsigned brow = (unsigned)(m0 + rl);
        const unsigned bb = brow / 4000u;
        const int sel = (bb != b0);
        float rs = 0.f;
#pragma unroll
        for (int bi = 0; bi < 2; ++bi) {
          float s = acc[mi][bi][reg] + (sel ? av1v[bi] : av0v[bi]);
          rs += gvr[bi] * tanh_fast(s);
        }
        rs += __shfl_xor(rs, 1);
        rs += __shfl_xor(rs, 2);
        rs += __shfl_xor(rs, 4);
        rs += __shfl_xor(rs, 8);
        rs += __shfl_xor(rs, 16);
        if (ln31 == 0) P[wv * 64 + (rl & 63)] = rs;
      }
    }
  }
  __syncthreads();

  // cross-wave pair sum + store e (256 outputs: 2 heads x 128 rows)
  if (tid < 256) {
    const float* P = (const float*)(smem + 8192);
    const int hl = tid >> 7, rl = tid & 127;
    const int wmf = rl >> 6, r64 = rl & 63;
    const float ev = P[(wmf * 4 + hl * 2) * 64 + r64] + P[(wmf * 4 + hl * 2 + 1) * 64 + r64];
    const unsigned brow = (unsigned)(m0 + rl);
    const unsigned bb = brow / 4000u;
    const unsigned tt = brow - bb * 4000u;
    e_out[((size_t)bb * H_ + nh * 2 + hl) * T_ + tt] = ev;
  }
#undef MSTEP
#undef CBAR
}

// ---------------------------------------------------------------------------
__global__ __launch_bounds__(256) void k_msum(const float* __restrict__ e_in,
                                              float2* __restrict__ msum) {
  const int bh = blockIdx.x;
  const float* er = e_in + (size_t)bh * T_;
  __shared__ float red[256];
  const int tid = threadIdx.x;
  float m = -1e30f;
  for (int t = tid; t < T_; t += 256) m = fmaxf(m, er[t]);
  red[tid] = m;
  __syncthreads();
  for (int s = 128; s > 0; s >>= 1) {
    if (tid < s) red[tid] = fmaxf(red[tid], red[tid + s]);
    __syncthreads();
  }
  m = red[0];
  __syncthreads();
  float sum = 0.f;
  for (int t = tid; t < T_; t += 256) sum += __expf(er[t] - m);
  red[tid] = sum;
  __syncthreads();
  for (int s = 128; s > 0; s >>= 1) {
    if (tid < s) red[tid] += red[tid + s];
    __syncthreads();
  }
  if (tid == 0) msum[bh] = make_float2(m, 1.0f / red[0]);
}

// ---------------------------------------------------------------------------
__global__ __launch_bounds__(128) void k_ctx(const float* __restrict__ enc,
                                             const float* __restrict__ e_in,
                                             const float2* __restrict__ msum,
                                             float* __restrict__ wout,
                                             float* __restrict__ partial) {
  const int b = blockIdx.x, tc = blockIdx.y;
  const int t0 = tc * CH_;
  const int tid = threadIdx.x;
  __shared__ float wls[H_ * CH_];
  for (int i = tid; i < H_ * CH_; i += 128) {
    const int h = i / CH_, tt = i - h * CH_;
    const float2 ms = msum[b * H_ + h];
    const float w = __expf(e_in[((size_t)b * H_ + h) * T_ + t0 + tt] - ms.x) * ms.y;
    wls[i] = w;
    wout[((size_t)h * B_ + b) * T_ + t0 + tt] = w;
  }
  __syncthreads();
  float4 a0 = {0,0,0,0}, a1 = {0,0,0,0}, a2 = {0,0,0,0}, a3 = {0,0,0,0};
  const float4* enc4 = (const float4*)enc;
  const size_t ebase = ((size_t)b * T_ + t0) * 128 + tid;
#pragma unroll 8
  for (int tt = 0; tt < CH_; ++tt) {
    const float4 x = enc4[ebase + (size_t)tt * 128];
    const float w0 = wls[tt], w1 = wls[CH_ + tt], w2 = wls[2 * CH_ + tt], w3 = wls[3 * CH_ + tt];
    a0.x += w0 * x.x; a0.y += w0 * x.y; a0.z += w0 * x.z; a0.w += w0 * x.w;
    a1.x += w1 * x.x; a1.y += w1 * x.y; a1.z += w1 * x.z; a1.w += w1 * x.w;
    a2.x += w2 * x.x; a2.y += w2 * x.y; a2.z += w2 * x.z; a2.w += w2 * x.w;
    a3.x += w3 * x.x; a3.y += w3 * x.y; a3.z += w3 * x.z; a3.w += w3 * x.w;
  }
  float4* p4 = (float4*)partial;
  const size_t pbase = (((size_t)tc * B_ + b) * H_) * 128 + tid;
  p4[pbase] = a0;
  p4[pbase + 128] = a1;
  p4[pbase + 256] = a2;
  p4[pbase + 384] = a3;
}

// ---------------------------------------------------------------------------
__global__ __launch_bounds__(256) void k_out_part(const float* __restrict__ partial,
                                                  const float* __restrict__ Wo,
                                                  float* __restrict__ p2) {
  const int b = blockIdx.x;
  const int o = blockIdx.y * 256 + threadIdx.x;
  const int kc = blockIdx.z;
  __shared__ float cS[256];
  const int he0 = kc * 256;
  {
    float s = 0.f;
#pragma unroll
    for (int tc = 0; tc < TC_; ++tc)
      s += partial[((size_t)tc * B_ + b) * (H_ * E_) + he0 + threadIdx.x];
    cS[threadIdx.x] = s;
  }
  __syncthreads();
  float s = 0.f;
#pragma unroll 8
  for (int i = 0; i < 256; ++i) s += cS[i] * Wo[(size_t)(he0 + i) * O_ + o];
  p2[((size_t)kc * B_ + b) * O_ + o] = s;
}

__global__ __launch_bounds__(512) void k_out_fin(const float* __restrict__ p2,
                                                 const float* __restrict__ bo,
                                                 float* __restrict__ out) {
  const int b = blockIdx.x, o = threadIdx.x;
  float s = bo[o];
#pragma unroll
  for (int kc = 0; kc < 8; ++kc) s += p2[((size_t)kc * B_ + b) * O_ + o];
  out[b * O_ + o] = s;
}

// ---------------------------------------------------------------------------
extern "C" void kernel_launch(void* const* d_in, const int* in_sizes, int n_in,
                              void* d_out, int out_size, void* d_ws, size_t ws_size,
                              hipStream_t stream) {
  (void)in_sizes; (void)n_in; (void)out_size; (void)ws_size;
  const float* enc      = (const float*)d_in[0];
  // d_in[1] = enc_len : unused by the reference
  const float* dec_z    = (const float*)d_in[2];
  const float* att_prev = (const float*)d_in[3];
  const float* Wenc     = (const float*)d_in[4];
  const float* benc     = (const float*)d_in[5];
  const float* Wdec     = (const float*)d_in[6];
  const float* Watt     = (const float*)d_in[7];
  const float* conv_w   = (const float*)d_in[8];
  const float* gv       = (const float*)d_in[9];
  const float* Wo       = (const float*)d_in[10];
  const float* bo       = (const float*)d_in[11];

  float* out  = (float*)d_out;
  float* wout = out + B_ * O_;  // ws [H,B,T]

  char* wsb = (char*)d_ws;
  float*  e_buf   = (float*)(wsb);               // 1,024,000 B
  char*   convpad = wsb + 1024000;               // 8,192,000 B
  char*   wbs     = wsb + 9216000;               //   524,288 B
  char*   wattb   = wsb + 9740288;               //    16,384 B
  float*  addv4   = (float*)(wsb + 9756672);     //   131,072 B
  float2* msum    = (float2*)(wsb + 9887744);    //       512 B
  float*  partial = (float*)(wsb + 9888256);     // 6,553,600 B
  float*  p2      = (float*)(wsb + 16441856);    //   262,144 B

  hipLaunchKernelGGL(k_prep, dim3(257), dim3(256), 0, stream,
                     Wenc, Watt, dec_z, Wdec, benc, wbs, wattb, addv4);
  hipLaunchKernelGGL(k_conv, dim3(B_ * H_, 16), dim3(256), 0, stream, att_prev, conv_w, convpad);
  hipLaunchKernelGGL(k_fused_e_mfma, dim3(500, 2), dim3(512), 0, stream,
                     enc, wbs, convpad, wattb, addv4, gv, e_buf);
  hipLaunchKernelGGL(k_msum, dim3(B_ * H_), dim3(256), 0, stream, e_buf, msum);
  hipLaunchKernelGGL(k_ctx, dim3(B_, TC_), dim3(128), 0, stream, enc, e_buf, msum, wout, partial);
  hipLaunchKernelGGL(k_out_part, dim3(B_, O_ / 256, 8), dim3(256), 0, stream, partial, Wo, p2);
  hipLaunchKernelGGL(k_out_fin, dim3(B_), dim3(512), 0, stream, p2, bo, out);
}